// Round 6
// baseline (528.372 us; speedup 1.0000x reference)
//
#include <hip/hip_runtime.h>
#include <hip/hip_bf16.h>

typedef __attribute__((ext_vector_type(8))) short bf16x8;
typedef __attribute__((ext_vector_type(4))) float f32x4;

__device__ __forceinline__ unsigned short f2bf(float f) {
  __hip_bfloat16 h = __float2bfloat16(f);
  return *reinterpret_cast<unsigned short*>(&h);
}

__device__ __forceinline__ void gld_lds16(void* lds, const void* g) {
  __builtin_amdgcn_global_load_lds(
      (const __attribute__((address_space(1))) unsigned int*)g,
      (__attribute__((address_space(3))) unsigned int*)lds, 16, 0, 0);
}

// ---------------------------------------------------------------------------
// Kernel 1: offset conv (fp64 accumulate) + gather + fp32->bf16 cast.
// (unchanged this round — isolate the k3 delta)
// ---------------------------------------------------------------------------
__global__ __launch_bounds__(256) void k1_offs_gather(
    const float* __restrict__ in, const float* __restrict__ w_off,
    const float* __restrict__ b_off, unsigned short* __restrict__ samp) {
  __shared__ float tile[3][128][34];
  __shared__ float wlf[9 * 64];
  __shared__ double dsum[2][128][2];
  __shared__ int lin_lds[128];

  const int bid = blockIdx.x;
  const int b = bid >> 7, h = bid & 127;
  const int t = threadIdx.x;
  const int w = t & 127, half = t >> 7, ch0 = half * 16;

  double a0 = 0.0, a1 = 0.0;

  for (int c0 = 0; c0 < 256; c0 += 32) {
    __syncthreads();
    for (int i = t; i < 576; i += 256) {
      int tap = i >> 6, r = i & 63;
      wlf[i] = w_off[tap * 512 + c0 * 2 + r];
    }
    for (int dr = 0; dr < 3; ++dr) {
      int hh = h + dr - 1;
      if ((unsigned)hh < 128u) {
        const float* rbase = in + ((size_t)(b * 128 + hh) * 128) * 256 + c0;
        #pragma unroll
        for (int it = 0; it < 4; ++it) {
          int idx = it * 256 + t;
          int ww = idx >> 3, cq = idx & 7;
          const float4 v = *(const float4*)(rbase + ww * 256 + cq * 4);
          float* dst = &tile[dr][ww][cq * 4];
          *(float2*)dst = make_float2(v.x, v.y);
          *(float2*)(dst + 2) = make_float2(v.z, v.w);
        }
      } else {
        #pragma unroll
        for (int it = 0; it < 4; ++it) {
          int idx = it * 256 + t;
          int ww = idx >> 3, cq = idx & 7;
          float* dst = &tile[dr][ww][cq * 4];
          *(float2*)dst = make_float2(0.f, 0.f);
          *(float2*)(dst + 2) = make_float2(0.f, 0.f);
        }
      }
    }
    __syncthreads();
    #pragma unroll
    for (int dr = 0; dr < 3; ++dr) {
      #pragma unroll
      for (int dc = 0; dc < 3; ++dc) {
        int wsrc = w + dc - 1;
        if ((unsigned)wsrc >= 128u) continue;
        const float2* tp2 = (const float2*)&tile[dr][wsrc][ch0];
        const float2* wp2 = (const float2*)&wlf[(dr * 3 + dc) * 64 + ch0 * 2];
        #pragma unroll
        for (int c2 = 0; c2 < 8; ++c2) {
          float2 v = tp2[c2];
          float2 wa = wp2[2 * c2];
          float2 wb = wp2[2 * c2 + 1];
          a0 += (double)v.x * (double)wa.x;
          a1 += (double)v.x * (double)wa.y;
          a0 += (double)v.y * (double)wb.x;
          a1 += (double)v.y * (double)wb.y;
        }
      }
    }
  }
  dsum[half][w][0] = a0;
  dsum[half][w][1] = a1;
  __syncthreads();
  if (t < 128) {
    double o0 = dsum[0][t][0] + dsum[1][t][0] + (double)b_off[0];
    double o1 = dsum[0][t][1] + dsum[1][t][1] + (double)b_off[1];
    double yd = (double)h + o0;
    double xd = (double)t + o1;
    yd = yd < 0.0 ? 0.0 : (yd > 127.0 ? 127.0 : yd);
    xd = xd < 0.0 ? 0.0 : (xd > 127.0 ? 127.0 : xd);
    int y = (int)yd, x = (int)xd;
    lin_lds[t] = y * 128 + x;
  }
  __syncthreads();
  const float* imgbase = in + (size_t)b * 16384 * 256;
  unsigned short* obase = samp + (size_t)bid * 128 * 256;
  for (int it = 0; it < 32; ++it) {
    int idx = it * 256 + t;
    int px = idx >> 6, cv = idx & 63;
    const float4 v = *(const float4*)(imgbase + (size_t)lin_lds[px] * 256 + cv * 4);
    ushort4 o;
    o.x = f2bf(v.x); o.y = f2bf(v.y); o.z = f2bf(v.z); o.w = f2bf(v.w);
    *(ushort4*)(obase + px * 256 + cv * 4) = o;
  }
}

// ---------------------------------------------------------------------------
// Kernel 2: w_def (3,3,256,256)[tap][k][n] fp32 -> wT[tap][n][k] bf16
// ---------------------------------------------------------------------------
__global__ __launch_bounds__(256) void k2_wT(const float* __restrict__ wdef,
                                             unsigned short* __restrict__ wT) {
  int g = blockIdx.x * 256 + threadIdx.x;
  int tap = g >> 16;
  int n = (g >> 8) & 255;
  int k = g & 255;
  wT[g] = f2bf(wdef[((size_t)tap * 256 + k) * 256 + n]);
}

// ---------------------------------------------------------------------------
// Kernel 3: implicit-GEMM 3x3 SAME conv, bf16 MFMA, 2-PHASE schedule.
// BM=256, BN=256, BK=32, 72 K-steps. 8 waves (2M x 4N), per-wave 128x64.
// 4-deep LDS ring, per step TWO phases (m201/T3+T4 mechanism):
//   phA: reads fb[0..3]+af[0..3] -> BAR -> 16 MFMA (acc mi0..3) -> BAR
//   phB: reads af[4..7]; stage(t+3); vmcnt(8) -> BAR -> 16 MFMA (mi4..7) -> BAR
// Consecutive phases write disjoint acc quadrants -> MFMA issue is
// dependency-free across phases; reads(p+1) overlap matrix-pipe drain of (p).
// Ledger: RAW -- slot t+1 drained by phB(t) vmcnt(8) (outstanding = stages
// t+1,t+2,t+3 = 12 loads) before its BAR; read at phA(t+1). WAR -- stage(t+3)
// writes slot (t-1)&3; its reads are older lgkm ops than phA(t)'s reads and
// LDS completes in-order per wave, so all done before phA(t)'s BAR < stage.
// Tail: VM = 4 (t=69), 0 (t=70), 0 (t=71, no-op).
// ---------------------------------------------------------------------------
__global__ __launch_bounds__(512, 2) void k3_conv(
    const unsigned short* __restrict__ samp, const unsigned short* __restrict__ wT,
    const float* __restrict__ b_def, float* __restrict__ out,
    const unsigned short* __restrict__ zerobuf) {
  __shared__ __align__(16) unsigned char smem[131072];  // A ring 64KB | B ring 64KB

  // T1: bijective XCD swizzle (grid 1024 % 8 == 0)
  const int bid0 = blockIdx.x;
  const int mt = (bid0 & 7) * 128 + (bid0 >> 3);
  const int bimg = mt >> 6;
  const int h0 = (mt & 63) * 2;

  const int tid = threadIdx.x;
  const int lane = tid & 63, wave = tid >> 6;
  const int wr = wave >> 2, wc = wave & 3;
  const int r15 = lane & 15, g4 = lane >> 4;
  const int g4eff = g4 ^ ((r15 >> 1) & 3);   // read-side bank swizzle

  int aoff[8], boff[4];
  #pragma unroll
  for (int mi = 0; mi < 8; ++mi)
    aoff[mi] = (wr * 128 + mi * 16 + r15) * 32 + g4eff * 8;
  #pragma unroll
  for (int ni = 0; ni < 4; ++ni)
    boff[ni] = (wc * 64 + ni * 16 + r15) * 32 + g4eff * 8;

  // ---- staging precompute (hoisted) ----
  const int chq = tid & 3;
  const int pix = tid >> 2;
  const int chs = chq ^ ((pix >> 1) & 3);  // inverse swizzle on global source
  const unsigned short* pA[2];
  const unsigned short* pB[2];
  unsigned vmask[2];
  #pragma unroll
  for (int it = 0; it < 2; ++it) {
    const int hh = h0 + it;
    pA[it] = samp + ((size_t)(bimg * 128 + hh) * 128 + pix) * 256 + chs * 8;
    pB[it] = wT + (size_t)(it * 128 + pix) * 256 + chs * 8;
    unsigned m = 0;
    #pragma unroll
    for (int tap = 0; tap < 9; ++tap) {
      const int dr = tap / 3 - 1, dc = tap % 3 - 1;
      if ((unsigned)(hh + dr) < 128u && (unsigned)(pix + dc) < 128u)
        m |= 1u << tap;
    }
    vmask[it] = m;
  }
  const unsigned short* zb = zerobuf + chq * 8;

  f32x4 acc[8][4];
  #pragma unroll
  for (int i = 0; i < 8; ++i)
    #pragma unroll
    for (int j = 0; j < 4; ++j) acc[i][j] = (f32x4){0.f, 0.f, 0.f, 0.f};

  auto stage = [&](int ts) {
    const int tap = ts >> 3, kc = ts & 7;
    const int q = (tap * 11) >> 5;
    const int tapdelta = ((q - 1) * 128 + (tap - q * 3 - 1)) * 256 + kc * 32;
    const int boffg = tap * 65536 + kc * 32;
    unsigned char* Ad = smem + (size_t)(ts & 3) * 16384;
    unsigned char* Bd = smem + 65536 + (size_t)(ts & 3) * 16384;
    #pragma unroll
    for (int it = 0; it < 2; ++it)
      gld_lds16(Bd + (it * 512 + tid) * 16, pB[it] + boffg);
    #pragma unroll
    for (int it = 0; it < 2; ++it) {
      const unsigned short* src =
          ((vmask[it] >> tap) & 1) ? (pA[it] + tapdelta) : zb;
      gld_lds16(Ad + (it * 512 + tid) * 16, src);
    }
  };

  auto readsA = [&](int T, bf16x8* af, bf16x8* fb) {
    const unsigned short* Ab = (const unsigned short*)(smem + (size_t)(T & 3) * 16384);
    const unsigned short* Bb = (const unsigned short*)(smem + 65536 + (size_t)(T & 3) * 16384);
    #pragma unroll
    for (int ni = 0; ni < 4; ++ni) fb[ni] = *(const bf16x8*)(Bb + boff[ni]);
    #pragma unroll
    for (int mi = 0; mi < 4; ++mi) af[mi] = *(const bf16x8*)(Ab + aoff[mi]);
  };
  auto readsB = [&](int T, bf16x8* af) {
    const unsigned short* Ab = (const unsigned short*)(smem + (size_t)(T & 3) * 16384);
    #pragma unroll
    for (int mi = 4; mi < 8; ++mi) af[mi] = *(const bf16x8*)(Ab + aoff[mi]);
  };
  auto mfmaA = [&](bf16x8* af, bf16x8* fb) {
    __builtin_amdgcn_s_setprio(1);
    #pragma unroll
    for (int mi = 0; mi < 4; ++mi)
      #pragma unroll
      for (int ni = 0; ni < 4; ++ni)
        acc[mi][ni] = __builtin_amdgcn_mfma_f32_16x16x32_bf16(
            af[mi], fb[ni], acc[mi][ni], 0, 0, 0);
    __builtin_amdgcn_s_setprio(0);
  };
  auto mfmaB = [&](bf16x8* af, bf16x8* fb) {
    __builtin_amdgcn_s_setprio(1);
    #pragma unroll
    for (int mi = 4; mi < 8; ++mi)
      #pragma unroll
      for (int ni = 0; ni < 4; ++ni)
        acc[mi][ni] = __builtin_amdgcn_mfma_f32_16x16x32_bf16(
            af[mi], fb[ni], acc[mi][ni], 0, 0, 0);
    __builtin_amdgcn_s_setprio(0);
  };

#define K3_STEP(T, VM, DO_STAGE)                            \
  {                                                         \
    bf16x8 af[8], fb[4];                                    \
    readsA(T, af, fb);                                      \
    asm volatile("" ::: "memory");                          \
    __builtin_amdgcn_s_barrier();                           \
    asm volatile("" ::: "memory");                          \
    mfmaA(af, fb);                                          \
    asm volatile("" ::: "memory");                          \
    __builtin_amdgcn_s_barrier();                           \
    asm volatile("" ::: "memory");                          \
    readsB(T, af);                                          \
    if (DO_STAGE) stage((T) + 3);                           \
    asm volatile("s_waitcnt vmcnt(" #VM ")" ::: "memory");  \
    __builtin_amdgcn_s_barrier();                           \
    asm volatile("" ::: "memory");                          \
    mfmaB(af, fb);                                          \
    asm volatile("" ::: "memory");                          \
    __builtin_amdgcn_s_barrier();                           \
    asm volatile("" ::: "memory");                          \
  }

  // prologue: fill 3 ring slots; make stage(0) visible everywhere
  stage(0); stage(1); stage(2);
  asm volatile("s_waitcnt vmcnt(8)" ::: "memory");
  __builtin_amdgcn_s_barrier();
  asm volatile("" ::: "memory");

  for (int t = 0; t < 69; ++t) K3_STEP(t, 8, true);
  K3_STEP(69, 4, false);
  K3_STEP(70, 0, false);
  K3_STEP(71, 0, false);
#undef K3_STEP

  // epilogue: +bias, fp32 store
  const int colg = wc * 64 + r15;
  float bias[4];
  #pragma unroll
  for (int ni = 0; ni < 4; ++ni) bias[ni] = b_def[colg + ni * 16];
  #pragma unroll
  for (int mi = 0; mi < 8; ++mi) {
    const int r0 = wr * 128 + mi * 16 + g4 * 4;
    #pragma unroll
    for (int j = 0; j < 4; ++j) {
      float* orow = out + ((size_t)mt * 256 + r0 + j) * 256 + colg;
      #pragma unroll
      for (int ni = 0; ni < 4; ++ni) orow[ni * 16] = acc[mi][ni][j] + bias[ni];
    }
  }
}

extern "C" void kernel_launch(void* const* d_in, const int* in_sizes, int n_in,
                              void* d_out, int out_size, void* d_ws, size_t ws_size,
                              hipStream_t stream) {
  const float* in = (const float*)d_in[0];     // (16,128,128,256)
  const float* w_off = (const float*)d_in[1];  // (3,3,256,2)
  const float* b_off = (const float*)d_in[2];  // (2,)
  const float* w_def = (const float*)d_in[3];  // (3,3,256,256)
  const float* b_def = (const float*)d_in[4];  // (256,)
  float* out = (float*)d_out;

  char* ws = (char*)d_ws;
  unsigned short* zerobuf = (unsigned short*)ws;                 // 4 KB zeros
  unsigned short* wT = (unsigned short*)(ws + 4096);             // 1,179,648 B
  unsigned short* samp = (unsigned short*)(ws + 4096 + 1179648); // 134,217,728 B

  hipMemsetAsync(ws, 0, 4096, stream);
  hipLaunchKernelGGL(k2_wT, dim3(2304), dim3(256), 0, stream, w_def, wT);
  hipLaunchKernelGGL(k1_offs_gather, dim3(2048), dim3(256), 0, stream,
                     in, w_off, b_off, samp);
  hipLaunchKernelGGL(k3_conv, dim3(1024), dim3(512), 0, stream,
                     samp, wT, b_def, out, zerobuf);
}